// Round 4
// baseline (110.115 us; speedup 1.0000x reference)
//
#include <hip/hip_runtime.h>
#include <math.h>

#define SLICES 32
#define ROWS_PER_SLICE 16
#define NBOXES 160
#define THREADS 256

static __device__ __forceinline__ float fast_sigmoid(float x) {
    // 1 / (1 + e^-x); raw v_rcp_f32 (1 ulp) is plenty for a 1e-4 threshold.
    return __builtin_amdgcn_rcpf(1.0f + __expf(-x));
}

// One block per (slice, batch). The 8 float4 pred loads are issued AROUND the
// box/mask phase (4 before, 4 after) so the ~900-cycle global latency and the
// HBM drain overlap the mask-build VALU work instead of serializing with it.
__global__ __launch_bounds__(THREADS) void paint_reduce_kernel(
    const float* __restrict__ pred, const int* __restrict__ targets,
    float* __restrict__ partials)
{
    __shared__ int s_x1[NBOXES], s_x2[NBOXES];
    __shared__ unsigned s_y1[NBOXES], s_y2[NBOXES];
    __shared__ int s_wcnt[4];
    __shared__ unsigned s_mask[ROWS_PER_SLICE * 16];  // 16 rows x 512 bits
    __shared__ float s_red[4 * 3];

    const int t = threadIdx.x;
    const int slice = blockIdx.x;
    const int b = blockIdx.y;
    const int r0 = slice * ROWS_PER_SLICE;
    const int lane = t & 63, wave = t >> 6;

    // ---- Issue targets load first (needed soonest). ----
    int4 g = make_int4(0, 0, 0, 0);
    if (t < NBOXES) g = ((const int4*)targets)[(size_t)b * NBOXES + t];

    // ---- Issue first 4 pred loads; they drain during the mask phase. ----
    const float4* p4 = (const float4*)pred;
    const int col4 = t & 127;
    const int rb = t >> 7;  // 0 or 1
    const size_t g0 = (size_t)b * 65536 + (size_t)r0 * 128 + col4;
    float4 v0 = p4[g0 + (size_t)(rb + 0) * 128];
    float4 v1 = p4[g0 + (size_t)(rb + 2) * 128];
    float4 v2 = p4[g0 + (size_t)(rb + 4) * 128];
    float4 v3 = p4[g0 + (size_t)(rb + 6) * 128];
    __builtin_amdgcn_sched_barrier(0);  // pin: loads stay ABOVE the mask phase

    // ---- Box clip + ballot compaction (no LDS atomics). ----
    bool keep = false;
    int cx1 = 0, cx2 = 0;
    unsigned cy1 = 0, cy2 = 0;
    if (t < NBOXES) {
        int x1 = min(g.x, 512), y1 = min(g.y, 512);
        int x2 = min(g.x + g.z, 512), y2 = min(g.y + g.w, 512);
        cx1 = max(x1, r0); cx2 = min(x2, r0 + ROWS_PER_SLICE);
        cy1 = (unsigned)y1; cy2 = (unsigned)y2;
        keep = (cx2 > cx1) && (y2 > y1);
    }
    const unsigned long long bal = __ballot(keep);
    if (lane == 0) s_wcnt[wave] = (int)__popcll(bal);
    __syncthreads();
    int wbase_cnt = 0;
    for (int w = 0; w < wave; ++w) wbase_cnt += s_wcnt[w];
    const int nb = s_wcnt[0] + s_wcnt[1] + s_wcnt[2] + s_wcnt[3];
    if (keep) {
        const int idx = wbase_cnt + (int)__popcll(bal & ((1ull << lane) - 1ull));
        s_x1[idx] = cx1; s_x2[idx] = cx2; s_y1[idx] = cy1; s_y2[idx] = cy2;
    }
    __syncthreads();

    // ---- Mask build: thread t owns row (t>>4), word (t&15). ----
    {
        const int row_l = t >> 4;
        const int w = t & 15;
        const int r = r0 + row_l;
        const unsigned wb = (unsigned)w * 32u;
        unsigned m = 0;
        for (int k = 0; k < nb; ++k) {
            if (r >= s_x1[k] && r < s_x2[k]) {
                unsigned lo = s_y1[k], hi = s_y2[k];
                lo = lo > wb ? lo : wb;
                hi = hi < wb + 32u ? hi : wb + 32u;
                if (hi > lo) {
                    unsigned n = hi - lo;
                    unsigned bits = (n >= 32u) ? 0xFFFFFFFFu : ((1u << n) - 1u);
                    m |= bits << (lo - wb);
                }
            }
        }
        s_mask[t] = m;
    }
    __syncthreads();

    // ---- Consume v0..v3 while issuing v4..v7. ----
    const int widx = col4 >> 3;
    const unsigned bb = (unsigned)(col4 & 7) * 4u;
    unsigned n0 = (s_mask[(rb +  0) * 16 + widx] >> bb) & 0xFu;
    unsigned n1 = (s_mask[(rb +  2) * 16 + widx] >> bb) & 0xFu;
    unsigned n2 = (s_mask[(rb +  4) * 16 + widx] >> bb) & 0xFu;
    unsigned n3 = (s_mask[(rb +  6) * 16 + widx] >> bb) & 0xFu;

    float4 v4 = p4[g0 + (size_t)(rb +  8) * 128];
    float4 v5 = p4[g0 + (size_t)(rb + 10) * 128];
    float4 v6 = p4[g0 + (size_t)(rb + 12) * 128];
    float4 v7 = p4[g0 + (size_t)(rb + 14) * 128];

    float psum = 0.0f, isum = 0.0f;
    int cnt = 0;
#define ACC(V, N)                                                       \
    {                                                                   \
        float s0 = fast_sigmoid((V).x);                                 \
        float s1 = fast_sigmoid((V).y);                                 \
        float s2 = fast_sigmoid((V).z);                                 \
        float s3 = fast_sigmoid((V).w);                                 \
        psum += (s0 + s1) + (s2 + s3);                                  \
        cnt += __popc(N);                                               \
        isum += (((N) & 1u) ? s0 : 0.0f) + (((N) & 2u) ? s1 : 0.0f)     \
              + (((N) & 4u) ? s2 : 0.0f) + (((N) & 8u) ? s3 : 0.0f);    \
    }
    ACC(v0, n0) ACC(v1, n1) ACC(v2, n2) ACC(v3, n3)

    unsigned n4 = (s_mask[(rb +  8) * 16 + widx] >> bb) & 0xFu;
    unsigned n5 = (s_mask[(rb + 10) * 16 + widx] >> bb) & 0xFu;
    unsigned n6 = (s_mask[(rb + 12) * 16 + widx] >> bb) & 0xFu;
    unsigned n7 = (s_mask[(rb + 14) * 16 + widx] >> bb) & 0xFu;
    ACC(v4, n4) ACC(v5, n5) ACC(v6, n6) ACC(v7, n7)
#undef ACC
    float csum = (float)cnt;

    // ---- Wave reduce + cross-wave via LDS. ----
    for (int off = 32; off > 0; off >>= 1) {
        psum += __shfl_down(psum, off);
        isum += __shfl_down(isum, off);
        csum += __shfl_down(csum, off);
    }
    if (lane == 0) {
        s_red[wave * 3 + 0] = psum;
        s_red[wave * 3 + 1] = isum;
        s_red[wave * 3 + 2] = csum;
    }
    __syncthreads();
    if (t == 0) {
        float P = 0, I = 0, C = 0;
        for (int w = 0; w < 4; ++w) {
            P += s_red[w * 3 + 0];
            I += s_red[w * 3 + 1];
            C += s_red[w * 3 + 2];
        }
        float* o = partials + ((size_t)b * SLICES + slice) * 3;
        o[0] = P; o[1] = I; o[2] = C;
    }
}

// One lane per batch: combine slice partials into the scalar loss.
__global__ __launch_bounds__(64) void final_kernel(
    const float* __restrict__ partials, float* __restrict__ out)
{
    const int b = threadIdx.x;  // 0..63
    double P = 0, I = 0, C = 0;
    for (int s = 0; s < SLICES; ++s) {
        const float* p = partials + ((size_t)b * SLICES + s) * 3;
        P += (double)p[0]; I += (double)p[1]; C += (double)p[2];
    }
    const double inter = 255.0 * I;
    const double tsum  = 255.0 * C;
    double loss = (inter + 1.0) / (P + tsum - inter + 1.0);
    for (int off = 32; off > 0; off >>= 1) loss += __shfl_down(loss, off);
    if (b == 0) out[0] = (float)(1.0 - loss / 64.0);
}

extern "C" void kernel_launch(void* const* d_in, const int* in_sizes, int n_in,
                              void* d_out, int out_size, void* d_ws, size_t ws_size,
                              hipStream_t stream) {
    const float* pred    = (const float*)d_in[0];  // (64,1,512,512) f32
    const int*   targets = (const int*)d_in[1];    // (64,5,32,4) i32
    float* out = (float*)d_out;                    // 1 f32 scalar
    float* partials = (float*)d_ws;                // 64*32*3 floats = 24 KiB

    dim3 grid(SLICES, 64);
    paint_reduce_kernel<<<grid, THREADS, 0, stream>>>(pred, targets, partials);
    final_kernel<<<1, 64, 0, stream>>>(partials, out);
}

// Round 5
// 106.698 us; speedup vs baseline: 1.0320x; 1.0320x over previous
//
#include <hip/hip_runtime.h>
#include <math.h>

#define SLICES 32
#define ROWS_PER_SLICE 16
#define NBOXES 160
#define THREADS 256

static __device__ __forceinline__ float fast_sigmoid(float x) {
    return __builtin_amdgcn_rcpf(1.0f + __expf(-x));
}

// One block per (slice, batch). Box phase is LDS-free: per-lane box load +
// clip, __ballot keep-mask, then a uniform ctz loop broadcasting each
// surviving box via v_readlane (SGPR). The old version did 4 ds_read_b32
// per box per thread = ~37k LDS-pipe cycles/CU — that was the 37us floor.
__global__ __launch_bounds__(THREADS, 8) void paint_reduce_kernel(
    const float* __restrict__ pred, const int* __restrict__ targets,
    float* __restrict__ partials)
{
    __shared__ unsigned s_mask[ROWS_PER_SLICE * 16];  // 16 rows x 512 bits
    __shared__ float s_red[4 * 3];

    const int t = threadIdx.x;
    const int slice = blockIdx.x;
    const int b = blockIdx.y;
    const int r0 = slice * ROWS_PER_SLICE;
    const int lane = t & 63, wave = t >> 6;

    // ---- Box loads: lane l handles boxes l, 64+l, 128+l (l<32). ----
    const int4* tg = (const int4*)targets + (size_t)b * NBOXES;
    int4 gb0 = tg[lane];
    int4 gb1 = tg[64 + lane];
    int4 gb2 = (lane < 32) ? tg[128 + lane] : make_int4(0, 0, 0, 0);

    // ---- Clip to this slice, pack to (x1|x2<<16), (y1|y2<<16). ----
    unsigned px0, py0, px1, py1, px2, py2;
    auto clip = [&](int4 g, unsigned& px, unsigned& py) -> bool {
        int x1 = min(g.x, 512), y1 = min(g.y, 512);
        int x2 = min(g.x + g.z, 512), y2 = min(g.y + g.w, 512);
        int cx1 = max(x1, r0), cx2 = min(x2, r0 + ROWS_PER_SLICE);
        px = (unsigned)cx1 | ((unsigned)cx2 << 16);
        py = (unsigned)y1 | ((unsigned)y2 << 16);
        return (cx2 > cx1) && (y2 > y1);
    };
    bool k0 = clip(gb0, px0, py0);
    bool k1 = clip(gb1, px1, py1);
    bool k2 = clip(gb2, px2, py2) && (lane < 32);
    unsigned long long m0 = __ballot(k0);
    unsigned long long m1 = __ballot(k1);
    unsigned long long m2 = __ballot(k2);

    // ---- Prefetch 4 of 8 pred float4 — drain under the scan loop. ----
    const float4* p4 = (const float4*)pred;
    const int col4 = t & 127;
    const int rb = t >> 7;  // 0 or 1
    const size_t gbase = (size_t)b * 65536 + (size_t)r0 * 128 + col4;
    float4 v0 = p4[gbase + (size_t)(rb + 0) * 128];
    float4 v1 = p4[gbase + (size_t)(rb + 2) * 128];
    float4 v2 = p4[gbase + (size_t)(rb + 4) * 128];
    float4 v3 = p4[gbase + (size_t)(rb + 6) * 128];
    __builtin_amdgcn_sched_barrier(0);

    // ---- Scan: uniform ctz loop, box data via v_readlane (no LDS). ----
    const int r = r0 + (t >> 4);          // this thread's row
    const unsigned wb = (unsigned)(t & 15) * 32u;  // word base bit
    unsigned m = 0;
    auto scan = [&](unsigned long long mk, unsigned px, unsigned py) {
        while (mk) {
            int k = (int)__builtin_ctzll(mk);
            mk &= mk - 1;
            unsigned rx = (unsigned)__builtin_amdgcn_readlane((int)px, k);
            unsigned ry = (unsigned)__builtin_amdgcn_readlane((int)py, k);
            int x1 = (int)(rx & 0xffffu), x2 = (int)(rx >> 16);
            unsigned y1 = ry & 0xffffu, y2 = ry >> 16;
            bool in_row = (r >= x1) && (r < x2);
            unsigned lo = y1 > wb ? y1 : wb;
            unsigned hi = y2 < wb + 32u ? y2 : wb + 32u;
            int nn = (int)hi - (int)lo;                  // valid iff 1..32
            unsigned bits = 0xFFFFFFFFu >> ((32 - nn) & 31);
            unsigned contrib = bits << ((lo - wb) & 31u);
            m |= (in_row && nn > 0) ? contrib : 0u;
        }
    };
    scan(m0, px0, py0);
    scan(m1, px1, py1);
    scan(m2, px2, py2);
    s_mask[t] = m;
    __syncthreads();   // also drains vmcnt: v0..v3 arrive under the scan

    // ---- Consume v0..v3; issue v4..v7. ----
    const int widx = col4 >> 3;
    const unsigned bb = (unsigned)(col4 & 7) * 4u;
    unsigned n0 = (s_mask[(rb +  0) * 16 + widx] >> bb) & 0xFu;
    unsigned n1 = (s_mask[(rb +  2) * 16 + widx] >> bb) & 0xFu;
    unsigned n2 = (s_mask[(rb +  4) * 16 + widx] >> bb) & 0xFu;
    unsigned n3 = (s_mask[(rb +  6) * 16 + widx] >> bb) & 0xFu;

    float4 v4 = p4[gbase + (size_t)(rb +  8) * 128];
    float4 v5 = p4[gbase + (size_t)(rb + 10) * 128];
    float4 v6 = p4[gbase + (size_t)(rb + 12) * 128];
    float4 v7 = p4[gbase + (size_t)(rb + 14) * 128];

    float psum = 0.0f, isum = 0.0f;
    int cnt = 0;
#define ACC(V, N)                                                       \
    {                                                                   \
        float s0 = fast_sigmoid((V).x);                                 \
        float s1 = fast_sigmoid((V).y);                                 \
        float s2 = fast_sigmoid((V).z);                                 \
        float s3 = fast_sigmoid((V).w);                                 \
        psum += (s0 + s1) + (s2 + s3);                                  \
        cnt += __popc(N);                                               \
        isum += (((N) & 1u) ? s0 : 0.0f) + (((N) & 2u) ? s1 : 0.0f)     \
              + (((N) & 4u) ? s2 : 0.0f) + (((N) & 8u) ? s3 : 0.0f);    \
    }
    ACC(v0, n0) ACC(v1, n1) ACC(v2, n2) ACC(v3, n3)

    unsigned n4 = (s_mask[(rb +  8) * 16 + widx] >> bb) & 0xFu;
    unsigned n5 = (s_mask[(rb + 10) * 16 + widx] >> bb) & 0xFu;
    unsigned n6 = (s_mask[(rb + 12) * 16 + widx] >> bb) & 0xFu;
    unsigned n7 = (s_mask[(rb + 14) * 16 + widx] >> bb) & 0xFu;
    ACC(v4, n4) ACC(v5, n5) ACC(v6, n6) ACC(v7, n7)
#undef ACC
    float csum = (float)cnt;

    // ---- Wave reduce + cross-wave via LDS. ----
    for (int off = 32; off > 0; off >>= 1) {
        psum += __shfl_down(psum, off);
        isum += __shfl_down(isum, off);
        csum += __shfl_down(csum, off);
    }
    if (lane == 0) {
        s_red[wave * 3 + 0] = psum;
        s_red[wave * 3 + 1] = isum;
        s_red[wave * 3 + 2] = csum;
    }
    __syncthreads();
    if (t == 0) {
        float P = 0, I = 0, C = 0;
        for (int w = 0; w < 4; ++w) {
            P += s_red[w * 3 + 0];
            I += s_red[w * 3 + 1];
            C += s_red[w * 3 + 2];
        }
        float* o = partials + ((size_t)b * SLICES + slice) * 3;
        o[0] = P; o[1] = I; o[2] = C;
    }
}

// One lane per batch: combine slice partials into the scalar loss.
__global__ __launch_bounds__(64) void final_kernel(
    const float* __restrict__ partials, float* __restrict__ out)
{
    const int b = threadIdx.x;  // 0..63
    double P = 0, I = 0, C = 0;
    for (int s = 0; s < SLICES; ++s) {
        const float* p = partials + ((size_t)b * SLICES + s) * 3;
        P += (double)p[0]; I += (double)p[1]; C += (double)p[2];
    }
    const double inter = 255.0 * I;
    const double tsum  = 255.0 * C;
    double loss = (inter + 1.0) / (P + tsum - inter + 1.0);
    for (int off = 32; off > 0; off >>= 1) loss += __shfl_down(loss, off);
    if (b == 0) out[0] = (float)(1.0 - loss / 64.0);
}

extern "C" void kernel_launch(void* const* d_in, const int* in_sizes, int n_in,
                              void* d_out, int out_size, void* d_ws, size_t ws_size,
                              hipStream_t stream) {
    const float* pred    = (const float*)d_in[0];  // (64,1,512,512) f32
    const int*   targets = (const int*)d_in[1];    // (64,5,32,4) i32
    float* out = (float*)d_out;                    // 1 f32 scalar
    float* partials = (float*)d_ws;                // 64*32*3 floats = 24 KiB

    dim3 grid(SLICES, 64);
    paint_reduce_kernel<<<grid, THREADS, 0, stream>>>(pred, targets, partials);
    final_kernel<<<1, 64, 0, stream>>>(partials, out);
}